// Round 5
// baseline (700.940 us; speedup 1.0000x reference)
//
#include <hip/hip_runtime.h>
#include <cfloat>

#define NROWS  32768
#define NCODES 8192
#define DDIM   256
#define KG     8                 // code-split; grid = 64 row-tiles * 8 = 512 blocks
#define CPB    (NCODES / KG)     // 1024 codes per block
#define CT     64                // codes per stage (32 KB tile), double-buffered
#define TPB    (CPB / CT)        // 16 stages per block
#define RPB    512               // rows per block (8 waves x 64 rows)

typedef __attribute__((ext_vector_type(8))) __bf16 bf16x8;
typedef __attribute__((ext_vector_type(4))) float  f32x4;

// ---- kernel A: codebook fp32 -> bf16 + fused esq ----
__global__ __launch_bounds__(256)
void cvt_cb(const float* __restrict__ cb, __bf16* __restrict__ cbb,
            float* __restrict__ esq) {
    const size_t i = (size_t)(blockIdx.x * 256 + threadIdx.x) * 8;
    const float4 f0 = *(const float4*)(cb + i);
    const float4 f1 = *(const float4*)(cb + i + 4);
    bf16x8 v;
    v[0] = (__bf16)f0.x; v[1] = (__bf16)f0.y; v[2] = (__bf16)f0.z; v[3] = (__bf16)f0.w;
    v[4] = (__bf16)f1.x; v[5] = (__bf16)f1.y; v[6] = (__bf16)f1.z; v[7] = (__bf16)f1.w;
    *(bf16x8*)(cbb + i) = v;
    float s = f0.x * f0.x + f0.y * f0.y + f0.z * f0.z + f0.w * f0.w
            + f1.x * f1.x + f1.y * f1.y + f1.z * f1.z + f1.w * f1.w;
    for (int o = 16; o > 0; o >>= 1) s += __shfl_down(s, o, 32);
    if ((threadIdx.x & 31) == 0) esq[i >> 8] = s;
}

// ---- kernel B: 4-waves/SIMD 64-rows/wave MFMA scan, 2 blocks/CU ----
// Post-mortem R4: MFMA 42% + VALU 31% + LDS 26% ~= 99% of wall -> the three
// pipes run nearly SERIALIZED at 2 waves/SIMD (a wave's chain is
// MFMA -> dependent argmin -> LDS reads; one partner wave can't hide it).
// VGPR=128 exactly, so HW allows 4 waves/SIMD -- the limiter was block
// geometry (64KB LDS -> 2 blocks/CU x 4 waves). Fix: 512-thr blocks
// (8 waves x 64 rows = 512 rows/block), KG=8 keeps grid at 512 = 2
// blocks/CU. Per-wave code identical (VGPR stays 128); LDS traffic and
// MFMA/SIMD invariant; only waves/SIMD doubles 2->4 so MFMA/VALU/LDS
// overlap across waves. Perfect overlap = MFMA demand ~66 us.
__global__ __launch_bounds__(512, 4)
void vq_mfma(const float* __restrict__ z, const __bf16* __restrict__ cbb,
             const float* __restrict__ esq,
             float* __restrict__ pV, int* __restrict__ pI) {
    __shared__ __align__(16) __bf16 Bb[2][CT * DDIM];   // 2 x 32 KB

    const int rowbase  = (blockIdx.x >> 3) * RPB;
    const int kg       = blockIdx.x & 7;
    const int codebase = kg * CPB;

    const int tid = threadIdx.x;
    const int w = tid >> 6, l = tid & 63;       // wave = row-group (64 rows)
    const int lm = l & 15, lq = l >> 4;
    const int loff = lm * DDIM + lq * 8;        // lane offset in a 16-code group
    // staging role: 32 pieces (j 0..7, g 0..3) of 1 KB; wave w takes
    // g = w&3, j = (w>>2)*4 + jj (4 pieces per wave)
    const int g = w & 3, jb = (w >> 2) * 4;

    // ---- stage 0 loads first (overlap with A conversion below) ----
#pragma unroll
    for (int jj = 0; jj < 4; ++jj) {
        const int j = jb + jj;
        __builtin_amdgcn_global_load_lds(
            (const __attribute__((address_space(1))) void*)
                (cbb + (size_t)(codebase + g * 16) * DDIM + j * 32 + loff),
            (__attribute__((address_space(3))) void*)(&Bb[0][(j * 4 + g) * 512]),
            16, 0, 0);
    }

    // ---- A prologue: 64 rows x 256 k per wave -> 32 bf16x8 frags (-2*z) ----
    bf16x8 Af[4][8];   // [row-seg][k-chunk] = 128 VGPRs
    {
        const float* zp = z + (size_t)(rowbase + w * 64 + lm) * DDIM + lq * 8;
#pragma unroll
        for (int s = 0; s < 4; ++s)
#pragma unroll
            for (int kc = 0; kc < 8; ++kc) {
                const float4 f0 = *(const float4*)(zp + s * 16 * DDIM + kc * 32);
                const float4 f1 = *(const float4*)(zp + s * 16 * DDIM + kc * 32 + 4);
                bf16x8 v;
                v[0] = (__bf16)(-2.f * f0.x); v[1] = (__bf16)(-2.f * f0.y);
                v[2] = (__bf16)(-2.f * f0.z); v[3] = (__bf16)(-2.f * f0.w);
                v[4] = (__bf16)(-2.f * f1.x); v[5] = (__bf16)(-2.f * f1.y);
                v[6] = (__bf16)(-2.f * f1.z); v[7] = (__bf16)(-2.f * f1.w);
                Af[s][kc] = v;
            }
    }

    // esq for stage 0 (ping-ponged; 4 regs per buffer)
    float evc[4], evn[4];
#pragma unroll
    for (int fc = 0; fc < 4; ++fc)
        evc[fc] = esq[codebase + fc * 16 + lm];

    float bestV[16];
    int   bestI[16];
#pragma unroll
    for (int s = 0; s < 16; ++s) { bestV[s] = FLT_MAX; bestI[s] = 0; }

    __syncthreads();   // stage 0 staged

    int buf = 0;
#pragma unroll 1
    for (int t = 0; t < TPB; ++t) {
        // issue next stage's 32 KB into the other buffer FIRST
        if (t + 1 < TPB) {
            const __bf16* base = cbb + (size_t)(codebase + (t + 1) * CT + g * 16) * DDIM;
#pragma unroll
            for (int jj = 0; jj < 4; ++jj) {
                const int j = jb + jj;
                __builtin_amdgcn_global_load_lds(
                    (const __attribute__((address_space(1))) void*)(base + j * 32 + loff),
                    (__attribute__((address_space(3))) void*)(&Bb[buf ^ 1][(j * 4 + g) * 512]),
                    16, 0, 0);
            }
        }
        {   // prefetch next stage's esq (registers; 4 loads)
            const int tn = (t + 1) & (TPB - 1);
#pragma unroll
            for (int fc = 0; fc < 4; ++fc)
                evn[fc] = esq[codebase + tn * CT + fc * 16 + lm];
        }

        const __bf16* Bc = &Bb[buf][0];
        // two col-half passes keep acc at 4x2x4 = 32 VGPRs
#pragma unroll
        for (int fch = 0; fch < 2; ++fch) {
            f32x4 acc[4][2];
#pragma unroll
            for (int fr = 0; fr < 4; ++fr)
#pragma unroll
                for (int fc = 0; fc < 2; ++fc) {
                    const float e = evc[fch * 2 + fc];
                    acc[fr][fc] = (f32x4){e, e, e, e};
                }

#pragma unroll
            for (int c = 0; c < 8; ++c) {
                const bf16x8 b0 = *(const bf16x8*)(Bc + (c * 4 + fch * 2 + 0) * 512 + l * 8);
                const bf16x8 b1 = *(const bf16x8*)(Bc + (c * 4 + fch * 2 + 1) * 512 + l * 8);
#pragma unroll
                for (int fr = 0; fr < 4; ++fr)
                    acc[fr][0] = __builtin_amdgcn_mfma_f32_16x16x32_bf16(
                        Af[fr][c], b0, acc[fr][0], 0, 0, 0);
#pragma unroll
                for (int fr = 0; fr < 4; ++fr)
                    acc[fr][1] = __builtin_amdgcn_mfma_f32_16x16x32_bf16(
                        Af[fr][c], b1, acc[fr][1], 0, 0, 0);
            }

            // fused argmin (tiles/halves/cols all ascend; strict <)
#pragma unroll
            for (int fr = 0; fr < 4; ++fr)
#pragma unroll
                for (int fc = 0; fc < 2; ++fc) {
                    const int colI = codebase + t * CT + (fch * 2 + fc) * 16 + lm;
#pragma unroll
                    for (int i = 0; i < 4; ++i) {
                        const float sc = acc[fr][fc][i];
                        const int slot = fr * 4 + i;
                        if (sc < bestV[slot]) { bestV[slot] = sc; bestI[slot] = colI; }
                    }
                }
        }
#pragma unroll
        for (int fc = 0; fc < 4; ++fc) evc[fc] = evn[fc];

        __syncthreads();   // drain covered by the sibling block on this CU
        buf ^= 1;
    }

    // cross-lane argmin over the 16 col-lanes (lane bits 0..3 = lm)
#pragma unroll
    for (int s = 0; s < 16; ++s) {
#pragma unroll
        for (int m = 1; m < 16; m <<= 1) {
            const float v2 = __shfl_xor(bestV[s], m);
            const int   i2 = __shfl_xor(bestI[s], m);
            if (v2 < bestV[s] || (v2 == bestV[s] && i2 < bestI[s])) {
                bestV[s] = v2; bestI[s] = i2;
            }
        }
    }
    // rows partition across waves: direct global writeout, no LDS reduction
    if (lm == 0) {
#pragma unroll
        for (int s = 0; s < 16; ++s) {   // row = w*64 + fr*16 + lq*4 + i
            const int rl = w * 64 + (s >> 2) * 16 + lq * 4 + (s & 3);
            const int row = rowbase + rl;
            pV[row * KG + kg] = bestV[s];
            pI[row * KG + kg] = bestI[s];
        }
    }
}

// ---- kernel C: combine K-groups, gather (fp32), STE out, loss partials ----
__global__ __launch_bounds__(256)
void vq_finalize(const float* __restrict__ z, const float* __restrict__ cb,
                 const float* __restrict__ pV, const int* __restrict__ pI,
                 float* __restrict__ out, float* __restrict__ bsum) {
    __shared__ float sSum[4];
    __shared__ int   sIdx[4];
    const int tid = threadIdx.x;
    const int rw = tid >> 6, lane = tid & 63;
    const int row = blockIdx.x * 4 + rw;

    if (lane == 0) {  // ascending kg = ascending index; strict < keeps first
        float v = pV[row * KG]; int bi = pI[row * KG];
#pragma unroll
        for (int q = 1; q < KG; ++q) {
            const float v2 = pV[row * KG + q]; const int i2 = pI[row * KG + q];
            if (v2 < v || (v2 == v && i2 < bi)) { v = v2; bi = i2; }
        }
        sIdx[rw] = bi;
    }
    __syncthreads();
    const int idx = sIdx[rw];

    const float4 zv = *(const float4*)(z  + (size_t)row * DDIM + lane * 4);
    const float4 ev = *(const float4*)(cb + (size_t)idx * DDIM + lane * 4);
    float4 d, o;
    d.x = ev.x - zv.x; d.y = ev.y - zv.y; d.z = ev.z - zv.z; d.w = ev.w - zv.w;
    o.x = zv.x + d.x;  o.y = zv.y + d.y;  o.z = zv.z + d.z;  o.w = zv.w + d.w;
    *(float4*)(out + (size_t)row * DDIM + lane * 4) = o;

    float s = d.x * d.x + d.y * d.y + d.z * d.z + d.w * d.w;
    for (int off = 32; off > 0; off >>= 1) s += __shfl_down(s, off);
    if (lane == 0) sSum[rw] = s;
    __syncthreads();
    if (tid == 0) bsum[blockIdx.x] = sSum[0] + sSum[1] + sSum[2] + sSum[3];
}

// ---- kernel D: loss ----
__global__ __launch_bounds__(256)
void loss_final(const float* __restrict__ bsum, float* __restrict__ out) {
    __shared__ float red[4];
    const int tid = threadIdx.x;
    float s = 0.f;
    for (int i = tid; i < NROWS / 4; i += 256) s += bsum[i];
    for (int off = 32; off > 0; off >>= 1) s += __shfl_down(s, off);
    const int wv = tid >> 6, lane = tid & 63;
    if (lane == 0) red[wv] = s;
    __syncthreads();
    if (tid == 0) {
        const float tot = red[0] + red[1] + red[2] + red[3];
        out[(size_t)NROWS * DDIM] = tot * (1.25f / (float)((size_t)NROWS * DDIM));
    }
}

extern "C" void kernel_launch(void* const* d_in, const int* in_sizes, int n_in,
                              void* d_out, int out_size, void* d_ws, size_t ws_size,
                              hipStream_t stream) {
    const float* z  = (const float*)d_in[0];
    const float* cb = (const float*)d_in[1];
    float* out = (float*)d_out;

    // bf16 codebook staged at head of d_out (4 MB; consumed by vq_mfma
    // before vq_finalize overwrites the region)
    __bf16* cbf = (__bf16*)d_out;

    // workspace carve (~2.1 MB)
    float* esq  = (float*)d_ws;                 // 8192
    float* pV   = esq + NCODES;                 // 32768*8
    int*   pI   = (int*)(pV + NROWS * KG);      // 32768*8
    float* bsum = (float*)(pI + NROWS * KG);    // 8192

    cvt_cb<<<NCODES * DDIM / 8 / 256, 256, 0, stream>>>(cb, cbf, esq);
    vq_mfma<<<(NROWS / RPB) * KG, 512, 0, stream>>>(z, cbf, esq, pV, pI);
    vq_finalize<<<NROWS / 4, 256, 0, stream>>>(z, cb, pV, pI, out, bsum);
    loss_final<<<1, 256, 0, stream>>>(bsum, out);
}

// Round 6
// 228.820 us; speedup vs baseline: 3.0633x; 3.0633x over previous
//
#include <hip/hip_runtime.h>
#include <cfloat>

#define NROWS  32768
#define NCODES 8192
#define DDIM   256
#define KG     4                 // code-split; grid = 128 row-tiles * 4 = 512 blocks
#define CPB    (NCODES / KG)     // 2048 codes per block
#define CT     64                // codes per stage (32 KB tile), double-buffered
#define TPB    (CPB / CT)        // 32 stages per block
#define RPB    256               // rows per block (4 waves x 64 rows)

typedef __attribute__((ext_vector_type(8))) __bf16 bf16x8;
typedef __attribute__((ext_vector_type(4))) float  f32x4;

// ---- kernel A: codebook fp32 -> bf16 + fused esq (+1.0 bias for key-packing) ----
// esq' = ||e||^2 + 1 makes the MFMA score s = esq' - 2 z.e land in [0.6, 1.4]:
// strictly positive floats compare monotonically as u32, enabling the packed
// (score|index) argmin key in kernel B.
__global__ __launch_bounds__(256)
void cvt_cb(const float* __restrict__ cb, __bf16* __restrict__ cbb,
            float* __restrict__ esq) {
    const size_t i = (size_t)(blockIdx.x * 256 + threadIdx.x) * 8;
    const float4 f0 = *(const float4*)(cb + i);
    const float4 f1 = *(const float4*)(cb + i + 4);
    bf16x8 v;
    v[0] = (__bf16)f0.x; v[1] = (__bf16)f0.y; v[2] = (__bf16)f0.z; v[3] = (__bf16)f0.w;
    v[4] = (__bf16)f1.x; v[5] = (__bf16)f1.y; v[6] = (__bf16)f1.z; v[7] = (__bf16)f1.w;
    *(bf16x8*)(cbb + i) = v;
    float s = f0.x * f0.x + f0.y * f0.y + f0.z * f0.z + f0.w * f0.w
            + f1.x * f1.x + f1.y * f1.y + f1.z * f1.z + f1.w * f1.w;
    for (int o = 16; o > 0; o >>= 1) s += __shfl_down(s, o, 32);
    if ((threadIdx.x & 31) == 0) esq[i >> 8] = s + 1.0f;
}

// ---- kernel B: R4 geometry + packed-key argmin + half-deep argmin pipeline ----
// Post-mortem R5: launch_bounds(512,4) halved the reg budget -> Af spilled to
// scratch (FETCH 70MB -> 1.96GB). 64 rows/wave is a hard 2-waves/SIMD wall;
// revert to R4 geometry (256 thr, 4 waves x 64 rows, KG=4, 2 blocks/CU).
// R4 residual: MFMA 42% + VALU ~35% serialized -- each wave's argmin DEPENDS
// on its just-computed acc. Fixes (geometry unchanged):
// (1) packed-key argmin: key = (bits(score)&0xFFFFE000)|colI; score in
//     [0.6,1.4] (esq biased +1) so u32-min == (value,index)-min with
//     smaller-index tie-break. 2 VALU ops/value (and_or + min_u32) vs 3,
//     and bestV/bestI 32 regs -> bestK 16 regs.
// (2) two named acc sets (accA = cols 0-31, accB = cols 32-63); argmin of
//     accB(t-1) issues among accA(t)'s MFMAs, argmin of accA(t) among
//     accB(t)'s MFMAs -> VALU is independent of in-flight MFMAs and hides
//     under the MFMA pipe instead of stalling the wave.
__global__ __launch_bounds__(256, 2)
void vq_mfma(const float* __restrict__ z, const __bf16* __restrict__ cbb,
             const float* __restrict__ esq, unsigned* __restrict__ pK) {
    __shared__ __align__(16) __bf16 Bb[2][CT * DDIM];   // 2 x 32 KB

    const int rowbase  = (blockIdx.x >> 2) * RPB;
    const int kg       = blockIdx.x & 3;
    const int codebase = kg * CPB;

    const int tid = threadIdx.x;
    const int w = tid >> 6, l = tid & 63;       // wave = row-group (64 rows)
    const int lm = l & 15, lq = l >> 4;
    const int loff = lm * DDIM + lq * 8;        // lane offset in a 16-code group

    // ---- stage 0 loads first (overlap with A conversion below) ----
    // wave w stages code-group w (16 codes) x 8 k-chunks; piece = j*4 + w
#pragma unroll
    for (int j = 0; j < 8; ++j) {
        __builtin_amdgcn_global_load_lds(
            (const __attribute__((address_space(1))) void*)
                (cbb + (size_t)(codebase + w * 16) * DDIM + j * 32 + loff),
            (__attribute__((address_space(3))) void*)(&Bb[0][(j * 4 + w) * 512]),
            16, 0, 0);
    }

    // ---- A prologue: 64 rows x 256 k per wave -> 32 bf16x8 frags (-2*z) ----
    bf16x8 Af[4][8];   // [row-seg][k-chunk] = 128 VGPRs
    {
        const float* zp = z + (size_t)(rowbase + w * 64 + lm) * DDIM + lq * 8;
#pragma unroll
        for (int s = 0; s < 4; ++s)
#pragma unroll
            for (int kc = 0; kc < 8; ++kc) {
                const float4 f0 = *(const float4*)(zp + s * 16 * DDIM + kc * 32);
                const float4 f1 = *(const float4*)(zp + s * 16 * DDIM + kc * 32 + 4);
                bf16x8 v;
                v[0] = (__bf16)(-2.f * f0.x); v[1] = (__bf16)(-2.f * f0.y);
                v[2] = (__bf16)(-2.f * f0.z); v[3] = (__bf16)(-2.f * f0.w);
                v[4] = (__bf16)(-2.f * f1.x); v[5] = (__bf16)(-2.f * f1.y);
                v[6] = (__bf16)(-2.f * f1.z); v[7] = (__bf16)(-2.f * f1.w);
                Af[s][kc] = v;
            }
    }

    // esq for stage 0 (ping-ponged; 4 regs per buffer)
    float evc[4], evn[4];
#pragma unroll
    for (int fc = 0; fc < 4; ++fc)
        evc[fc] = esq[codebase + fc * 16 + lm];

    unsigned bestK[16];
#pragma unroll
    for (int s = 0; s < 16; ++s) bestK[s] = 0xFFFFFFFFu;

    // accB dummy for the first pipelined argmin: 2.0f -> key 0x40000000|c,
    // strictly larger than any real key (max real = bits(1.4) = 0x3FB33333)
    f32x4 accB[4][2];
#pragma unroll
    for (int fr = 0; fr < 4; ++fr) {
        accB[fr][0] = (f32x4){2.f, 2.f, 2.f, 2.f};
        accB[fr][1] = (f32x4){2.f, 2.f, 2.f, 2.f};
    }
    int pB = codebase;   // colI base for accB's pending argmin

    __syncthreads();   // stage 0 staged

    int buf = 0;
#pragma unroll 1
    for (int t = 0; t < TPB; ++t) {
        // issue next stage's 32 KB into the other buffer FIRST
        if (t + 1 < TPB) {
            const __bf16* base = cbb + (size_t)(codebase + (t + 1) * CT + w * 16) * DDIM;
#pragma unroll
            for (int j = 0; j < 8; ++j) {
                __builtin_amdgcn_global_load_lds(
                    (const __attribute__((address_space(1))) void*)(base + j * 32 + loff),
                    (__attribute__((address_space(3))) void*)(&Bb[buf ^ 1][(j * 4 + w) * 512]),
                    16, 0, 0);
            }
        }
        {   // prefetch next stage's esq (registers; 4 loads)
            const int tn = (t + 1) & (TPB - 1);
#pragma unroll
            for (int fc = 0; fc < 4; ++fc)
                evn[fc] = esq[codebase + tn * CT + fc * 16 + lm];
        }

        const __bf16* Bc = &Bb[buf][0];

        // ---- half 0: MFMAs into accA (cols 0-31) ----
        f32x4 accA[4][2];
#pragma unroll
        for (int fr = 0; fr < 4; ++fr) {
            const float e0 = evc[0], e1 = evc[1];
            accA[fr][0] = (f32x4){e0, e0, e0, e0};
            accA[fr][1] = (f32x4){e1, e1, e1, e1};
        }
#pragma unroll
        for (int c = 0; c < 8; ++c) {
            const bf16x8 b0 = *(const bf16x8*)(Bc + (c * 4 + 0) * 512 + l * 8);
            const bf16x8 b1 = *(const bf16x8*)(Bc + (c * 4 + 1) * 512 + l * 8);
#pragma unroll
            for (int fr = 0; fr < 4; ++fr)
                accA[fr][0] = __builtin_amdgcn_mfma_f32_16x16x32_bf16(
                    Af[fr][c], b0, accA[fr][0], 0, 0, 0);
#pragma unroll
            for (int fr = 0; fr < 4; ++fr)
                accA[fr][1] = __builtin_amdgcn_mfma_f32_16x16x32_bf16(
                    Af[fr][c], b1, accA[fr][1], 0, 0, 0);
        }

        // ---- pipelined argmin on accB (stage t-1, cols 32-63) ----
        // independent of accA's in-flight MFMAs -> scheduler interleaves
        {
            const unsigned c0 = (unsigned)(pB + lm);
            const unsigned c1 = (unsigned)(pB + 16 + lm);
#pragma unroll
            for (int fr = 0; fr < 4; ++fr)
#pragma unroll
                for (int i = 0; i < 4; ++i) {
                    const int slot = fr * 4 + i;
                    const unsigned k0 = (__float_as_uint(accB[fr][0][i]) & 0xFFFFE000u) | c0;
                    const unsigned k1 = (__float_as_uint(accB[fr][1][i]) & 0xFFFFE000u) | c1;
                    const unsigned km = k0 < k1 ? k0 : k1;
                    if (km < bestK[slot]) bestK[slot] = km;
                }
        }

        // ---- half 1: MFMAs into accB (cols 32-63) ----
#pragma unroll
        for (int fr = 0; fr < 4; ++fr) {
            const float e2 = evc[2], e3 = evc[3];
            accB[fr][0] = (f32x4){e2, e2, e2, e2};
            accB[fr][1] = (f32x4){e3, e3, e3, e3};
        }
#pragma unroll
        for (int c = 0; c < 8; ++c) {
            const bf16x8 b2 = *(const bf16x8*)(Bc + (c * 4 + 2) * 512 + l * 8);
            const bf16x8 b3 = *(const bf16x8*)(Bc + (c * 4 + 3) * 512 + l * 8);
#pragma unroll
            for (int fr = 0; fr < 4; ++fr)
                accB[fr][0] = __builtin_amdgcn_mfma_f32_16x16x32_bf16(
                    Af[fr][c], b2, accB[fr][0], 0, 0, 0);
#pragma unroll
            for (int fr = 0; fr < 4; ++fr)
                accB[fr][1] = __builtin_amdgcn_mfma_f32_16x16x32_bf16(
                    Af[fr][c], b3, accB[fr][1], 0, 0, 0);
        }

        // ---- pipelined argmin on accA (stage t, cols 0-31) ----
        {
            const int base0 = codebase + t * CT;
            const unsigned c0 = (unsigned)(base0 + lm);
            const unsigned c1 = (unsigned)(base0 + 16 + lm);
#pragma unroll
            for (int fr = 0; fr < 4; ++fr)
#pragma unroll
                for (int i = 0; i < 4; ++i) {
                    const int slot = fr * 4 + i;
                    const unsigned k0 = (__float_as_uint(accA[fr][0][i]) & 0xFFFFE000u) | c0;
                    const unsigned k1 = (__float_as_uint(accA[fr][1][i]) & 0xFFFFE000u) | c1;
                    const unsigned km = k0 < k1 ? k0 : k1;
                    if (km < bestK[slot]) bestK[slot] = km;
                }
        }
        pB = codebase + t * CT + 32;

#pragma unroll
        for (int fc = 0; fc < 4; ++fc) evc[fc] = evn[fc];

        __syncthreads();   // drain covered by the sibling block on this CU
        buf ^= 1;
    }

    // epilogue: argmin on the last half-1
    {
        const unsigned c0 = (unsigned)(pB + lm);
        const unsigned c1 = (unsigned)(pB + 16 + lm);
#pragma unroll
        for (int fr = 0; fr < 4; ++fr)
#pragma unroll
            for (int i = 0; i < 4; ++i) {
                const int slot = fr * 4 + i;
                const unsigned k0 = (__float_as_uint(accB[fr][0][i]) & 0xFFFFE000u) | c0;
                const unsigned k1 = (__float_as_uint(accB[fr][1][i]) & 0xFFFFE000u) | c1;
                const unsigned km = k0 < k1 ? k0 : k1;
                if (km < bestK[slot]) bestK[slot] = km;
            }
    }

    // cross-lane u32-min over the 16 col-lanes (lane bits 0..3 = lm)
#pragma unroll
    for (int s = 0; s < 16; ++s) {
#pragma unroll
        for (int m = 1; m < 16; m <<= 1) {
            const unsigned k2 = (unsigned)__shfl_xor((int)bestK[s], m);
            if (k2 < bestK[s]) bestK[s] = k2;
        }
    }
    // rows partition across waves: direct global writeout
    if (lm == 0) {
#pragma unroll
        for (int s = 0; s < 16; ++s) {   // row = w*64 + fr*16 + lq*4 + i
            const int rl = w * 64 + (s >> 2) * 16 + lq * 4 + (s & 3);
            const int row = rowbase + rl;
            pK[row * KG + kg] = bestK[s];
        }
    }
}

// ---- kernel C: combine K-groups (u32 min), gather, STE out, loss partials ----
__global__ __launch_bounds__(256)
void vq_finalize(const float* __restrict__ z, const float* __restrict__ cb,
                 const unsigned* __restrict__ pK,
                 float* __restrict__ out, float* __restrict__ bsum) {
    __shared__ float sSum[4];
    __shared__ int   sIdx[4];
    const int tid = threadIdx.x;
    const int rw = tid >> 6, lane = tid & 63;
    const int row = blockIdx.x * 4 + rw;

    if (lane == 0) {  // u32 min over KG groups: value-min, smaller-index ties
        unsigned k = pK[row * KG];
#pragma unroll
        for (int q = 1; q < KG; ++q) {
            const unsigned k2 = pK[row * KG + q];
            if (k2 < k) k = k2;
        }
        sIdx[rw] = (int)(k & 0x1FFFu);
    }
    __syncthreads();
    const int idx = sIdx[rw];

    const float4 zv = *(const float4*)(z  + (size_t)row * DDIM + lane * 4);
    const float4 ev = *(const float4*)(cb + (size_t)idx * DDIM + lane * 4);
    float4 d, o;
    d.x = ev.x - zv.x; d.y = ev.y - zv.y; d.z = ev.z - zv.z; d.w = ev.w - zv.w;
    o.x = zv.x + d.x;  o.y = zv.y + d.y;  o.z = zv.z + d.z;  o.w = zv.w + d.w;
    *(float4*)(out + (size_t)row * DDIM + lane * 4) = o;

    float s = d.x * d.x + d.y * d.y + d.z * d.z + d.w * d.w;
    for (int off = 32; off > 0; off >>= 1) s += __shfl_down(s, off);
    if (lane == 0) sSum[rw] = s;
    __syncthreads();
    if (tid == 0) bsum[blockIdx.x] = sSum[0] + sSum[1] + sSum[2] + sSum[3];
}

// ---- kernel D: loss ----
__global__ __launch_bounds__(256)
void loss_final(const float* __restrict__ bsum, float* __restrict__ out) {
    __shared__ float red[4];
    const int tid = threadIdx.x;
    float s = 0.f;
    for (int i = tid; i < NROWS / 4; i += 256) s += bsum[i];
    for (int off = 32; off > 0; off >>= 1) s += __shfl_down(s, off);
    const int wv = tid >> 6, lane = tid & 63;
    if (lane == 0) red[wv] = s;
    __syncthreads();
    if (tid == 0) {
        const float tot = red[0] + red[1] + red[2] + red[3];
        out[(size_t)NROWS * DDIM] = tot * (1.25f / (float)((size_t)NROWS * DDIM));
    }
}

extern "C" void kernel_launch(void* const* d_in, const int* in_sizes, int n_in,
                              void* d_out, int out_size, void* d_ws, size_t ws_size,
                              hipStream_t stream) {
    const float* z  = (const float*)d_in[0];
    const float* cb = (const float*)d_in[1];
    float* out = (float*)d_out;

    // bf16 codebook staged at head of d_out (4 MB; consumed by vq_mfma
    // before vq_finalize overwrites the region)
    __bf16* cbf = (__bf16*)d_out;

    // workspace carve (~600 KB)
    float*    esq  = (float*)d_ws;               // 8192
    unsigned* pK   = (unsigned*)(esq + NCODES);  // 32768*4
    float*    bsum = (float*)(pK + NROWS * KG);  // 8192

    cvt_cb<<<NCODES * DDIM / 8 / 256, 256, 0, stream>>>(cb, cbf, esq);
    vq_mfma<<<(NROWS / RPB) * KG, 256, 0, stream>>>(z, cbf, esq, pK);
    vq_finalize<<<NROWS / 4, 256, 0, stream>>>(z, cb, pK, out, bsum);
    loss_final<<<1, 256, 0, stream>>>(bsum, out);
}